// Round 1
// baseline (1166.223 us; speedup 1.0000x reference)
//
#include <hip/hip_runtime.h>
#include <math.h>
#include <cstddef>

#define BB 4
#define LL 4096
#define DD 256
#define NST 8
#define RANK 16
#define HID 128
#define BL (BB*LL)          // 16384
#define BLD ((size_t)BL*DD) // 4194304

__device__ __forceinline__ float siluf(float x){ return x / (1.f + __expf(-x)); }
__device__ __forceinline__ float softplusf_(float x){
  return fmaxf(x, 0.f) + log1pf(__expf(-fabsf(x)));
}

// ---------------- RMSNorm: one 64-thread wave per token, 4 floats/lane ----------
__global__ __launch_bounds__(64) void rms_kernel(
    const float* __restrict__ x0, const float* __restrict__ w0, float* __restrict__ o0,
    const float* __restrict__ x1, const float* __restrict__ w1, float* __restrict__ o1)
{
  const float* x; const float* w; float* o;
  if (blockIdx.y == 0){ x = x0; w = w0; o = o0; } else { x = x1; w = w1; o = o1; }
  size_t tok = blockIdx.x;
  int lane = threadIdx.x;
  float4 v = ((const float4*)(x + tok*DD))[lane];
  float s = v.x*v.x + v.y*v.y + v.z*v.z + v.w*v.w;
  #pragma unroll
  for (int m = 1; m < 64; m <<= 1) s += __shfl_xor(s, m, 64);
  float scale = 1.f / (sqrtf(s) * (1.f/16.f) + 1e-6f);
  float4 wv = ((const float4*)w)[lane];
  float4 r;
  r.x = v.x*scale*wv.x; r.y = v.y*scale*wv.y; r.z = v.z*scale*wv.z; r.w = v.w*scale*wv.w;
  ((float4*)(o + tok*DD))[lane] = r;
}

// ---------------- Generic tiled fp32 GEMM: C = A @ Bw^T  (+ epilogue) ------------
// A: M x K (row stride lda), Bw: N x K row-major, C: M x N.
// EPI: 0 = none, 1 = C = acc + Add, 2 = C = softplus(acc + bias[col])
template<int BM, int BN, int BK, int TM, int TN, int EPI>
__global__ __launch_bounds__(256) void gemm_abt(
    const float* __restrict__ A, const float* __restrict__ Bw,
    float* __restrict__ C, const float* __restrict__ Add,
    const float* __restrict__ bias,
    int M, int N, int K, int lda, int flipA)
{
  __shared__ __align__(16) float As[BK][BM+4];
  __shared__ __align__(16) float Bs[BK][BN+4];
  int tid = threadIdx.x;
  int row0 = blockIdx.x * BM;
  int col0 = blockIdx.y * BN;
  int tr = tid / (BN/TN);
  int tc = tid % (BN/TN);
  float acc[TM][TN];
  #pragma unroll
  for (int i = 0; i < TM; i++)
    #pragma unroll
    for (int j = 0; j < TN; j++) acc[i][j] = 0.f;

  for (int k0 = 0; k0 < K; k0 += BK){
    #pragma unroll
    for (int e = tid; e < BM*BK; e += 256){
      int r = e / BK, c = e % BK;
      int pr = row0 + r;
      if (flipA){ int b = pr / LL; int t = pr % LL; pr = b*LL + (LL-1-t); }
      As[c][r] = A[(size_t)pr*lda + k0 + c];
    }
    #pragma unroll
    for (int e = tid; e < BN*BK; e += 256){
      int r = e / BK, c = e % BK;
      Bs[c][r] = Bw[(size_t)(col0 + r)*K + k0 + c];
    }
    __syncthreads();
    #pragma unroll
    for (int kk = 0; kk < BK; kk++){
      float a[TM], bf[TN];
      if constexpr (TM == 4){
        float4 av = *(const float4*)&As[kk][tr*TM];
        a[0]=av.x; a[1]=av.y; a[2]=av.z; a[3]=av.w;
      } else {
        #pragma unroll
        for (int i = 0; i < TM; i++) a[i] = As[kk][tr*TM + i];
      }
      if constexpr (TN == 4){
        float4 bv = *(const float4*)&Bs[kk][tc*TN];
        bf[0]=bv.x; bf[1]=bv.y; bf[2]=bv.z; bf[3]=bv.w;
      } else if constexpr (TN == 2){
        float2 bv = *(const float2*)&Bs[kk][tc*TN];
        bf[0]=bv.x; bf[1]=bv.y;
      } else {
        #pragma unroll
        for (int j = 0; j < TN; j++) bf[j] = Bs[kk][tc*TN + j];
      }
      #pragma unroll
      for (int i = 0; i < TM; i++)
        #pragma unroll
        for (int j = 0; j < TN; j++) acc[i][j] = fmaf(a[i], bf[j], acc[i][j]);
    }
    __syncthreads();
  }

  #pragma unroll
  for (int i = 0; i < TM; i++){
    int r = row0 + tr*TM + i;
    size_t base = (size_t)r*N + col0 + tc*TN;
    if constexpr (TN == 4){
      float4 v; v.x=acc[i][0]; v.y=acc[i][1]; v.z=acc[i][2]; v.w=acc[i][3];
      if constexpr (EPI == 1){
        float4 ad = *(const float4*)&Add[base];
        v.x += ad.x; v.y += ad.y; v.z += ad.z; v.w += ad.w;
      }
      if constexpr (EPI == 2){
        int cc = col0 + tc*TN;
        v.x = softplusf_(v.x + bias[cc+0]);
        v.y = softplusf_(v.y + bias[cc+1]);
        v.z = softplusf_(v.z + bias[cc+2]);
        v.w = softplusf_(v.w + bias[cc+3]);
      }
      *(float4*)&C[base] = v;
    } else {
      #pragma unroll
      for (int j = 0; j < TN; j++){
        float v = acc[i][j];
        if constexpr (EPI == 1) v += Add[base + j];
        if constexpr (EPI == 2) v = softplusf_(v + bias[col0 + tc*TN + j]);
        C[base + j] = v;
      }
    }
  }
}

// ---------------- Depthwise causal conv k=4 + SiLU (both directions) -------------
__global__ __launch_bounds__(256) void conv_kernel(
    const float* __restrict__ xin,
    const float* __restrict__ wf, const float* __restrict__ bf, float* __restrict__ of,
    const float* __restrict__ wb, const float* __restrict__ bb, float* __restrict__ ob)
{
  int dir = blockIdx.y;
  size_t gid = (size_t)blockIdx.x*256 + threadIdx.x;   // over BLD
  int c = (int)(gid % DD);
  int tok = (int)(gid / DD);
  int b = tok / LL, t = tok % LL;
  const float* w = dir ? wb : wf;
  const float* bi = dir ? bb : bf;
  float* o = dir ? ob : of;
  float acc = bi[c];
  #pragma unroll
  for (int k = 0; k < 4; k++){
    int tt = t - 3 + k;
    if (tt >= 0){
      int src_t = dir ? (LL-1-tt) : tt;
      acc = fmaf(w[c*4 + k], xin[((size_t)b*LL + src_t)*DD + c], acc);
    }
  }
  o[gid] = siluf(acc);
}

// ---------------- Selective scan: 8-lane group per (b,d) chain -------------------
__global__ __launch_bounds__(256) void scan_kernel(
    const float* __restrict__ xcf, const float* __restrict__ df,
    const float* __restrict__ xdf, const float* __restrict__ Alogf,
    const float* __restrict__ Dfp, float* __restrict__ yf,
    const float* __restrict__ xcb, const float* __restrict__ db,
    const float* __restrict__ xdb, const float* __restrict__ Alogb,
    const float* __restrict__ Dbp, float* __restrict__ yb)
{
  int dir = blockIdx.y;
  const float* xc; const float* dl; const float* xd; const float* Alog;
  const float* Dp; float* y;
  if (dir == 0){ xc=xcf; dl=df; xd=xdf; Alog=Alogf; Dp=Dfp; y=yf; }
  else         { xc=xcb; dl=db; xd=xdb; Alog=Alogb; Dp=Dbp; y=yb; }
  int tid = threadIdx.x;
  int grp = tid >> 3, n = tid & 7;
  int chain = blockIdx.x*32 + grp;      // 0..1023
  int b = chain >> 8, d = chain & 255;
  float A = -__expf(Alog[d*NST + n]);
  float Dd = Dp[d];
  float h = 0.f;
  const float* xc_p = xc + (size_t)b*LL*DD + d;
  const float* dl_p = dl + (size_t)b*LL*DD + d;
  const float* xd_p = xd + (size_t)b*LL*32;
  float* y_p = y + (size_t)b*LL*DD + d;

  const int SU = 8;
  float dly[SU], xvv[SU], bvv[SU], cvv[SU];
  #pragma unroll
  for (int u = 0; u < SU; u++){
    dly[u] = dl_p[(size_t)u*DD];
    xvv[u] = xc_p[(size_t)u*DD];
    bvv[u] = xd_p[u*32 + 16 + n];
    cvv[u] = xd_p[u*32 + 24 + n];
  }
  for (int t0 = 0; t0 < LL; t0 += SU){
    float nd[SU], nx[SU], nb[SU], nc[SU];
    int tn = t0 + SU;
    if (tn < LL){
      #pragma unroll
      for (int u = 0; u < SU; u++){
        nd[u] = dl_p[(size_t)(tn+u)*DD];
        nx[u] = xc_p[(size_t)(tn+u)*DD];
        nb[u] = xd_p[(tn+u)*32 + 16 + n];
        nc[u] = xd_p[(tn+u)*32 + 24 + n];
      }
    }
    #pragma unroll
    for (int u = 0; u < SU; u++){
      float dA = __expf(dly[u] * A);
      h = fmaf(dA, h, dly[u]*xvv[u]*bvv[u]);
      float p = h * cvv[u];
      p += __shfl_xor(p, 1, 8);
      p += __shfl_xor(p, 2, 8);
      p += __shfl_xor(p, 4, 8);
      if (n == 0) y_p[(size_t)(t0+u)*DD] = p + xvv[u]*Dd;
    }
    if (tn < LL){
      #pragma unroll
      for (int u = 0; u < SU; u++){ dly[u]=nd[u]; xvv[u]=nx[u]; bvv[u]=nb[u]; cvv[u]=nc[u]; }
    }
  }
}

// ---------------- Combine: y=(yf+flip(yb))/2 -> rmsnorm -> *silu(z) --------------
__global__ __launch_bounds__(64) void combine_kernel(
    const float* __restrict__ yf, const float* __restrict__ yb,
    const float* __restrict__ z, const float* __restrict__ wn,
    float* __restrict__ out)
{
  size_t tok = blockIdx.x;
  int b = (int)(tok / LL), t = (int)(tok % LL);
  int lane = threadIdx.x;
  float4 a = ((const float4*)(yf + tok*DD))[lane];
  float4 c = ((const float4*)(yb + ((size_t)b*LL + (LL-1-t))*DD))[lane];
  float4 v;
  v.x=(a.x+c.x)*0.5f; v.y=(a.y+c.y)*0.5f; v.z=(a.z+c.z)*0.5f; v.w=(a.w+c.w)*0.5f;
  float s = v.x*v.x + v.y*v.y + v.z*v.z + v.w*v.w;
  #pragma unroll
  for (int m = 1; m < 64; m <<= 1) s += __shfl_xor(s, m, 64);
  float scale = 1.f / (sqrtf(s)*(1.f/16.f) + 1e-6f);
  float4 wv = ((const float4*)wn)[lane];
  float4 zv = ((const float4*)(z + tok*DD))[lane];
  float4 r;
  r.x = v.x*scale*wv.x*siluf(zv.x);
  r.y = v.y*scale*wv.y*siluf(zv.y);
  r.z = v.z*scale*wv.z*siluf(zv.z);
  r.w = v.w*scale*wv.w*siluf(zv.w);
  ((float4*)(out + tok*DD))[lane] = r;
}

// ---------------- FF depthwise conv k=3 pad(1,1) + SiLU --------------------------
__global__ __launch_bounds__(256) void dwconv3_kernel(
    const float* __restrict__ m, const float* __restrict__ w,
    const float* __restrict__ bi, float* __restrict__ o)
{
  size_t gid = (size_t)blockIdx.x*256 + threadIdx.x;  // over BL*HID
  int c = (int)(gid % HID);
  int tok = (int)(gid / HID);
  int b = tok / LL, t = tok % LL;
  float acc = bi[c];
  #pragma unroll
  for (int k = 0; k < 3; k++){
    int tt = t - 1 + k;
    if (tt >= 0 && tt < LL)
      acc = fmaf(w[c*3 + k], m[((size_t)b*LL + tt)*HID + c], acc);
  }
  o[gid] = siluf(acc);
}

extern "C" void kernel_launch(void* const* d_in, const int* in_sizes, int n_in,
                              void* d_out, int out_size, void* d_ws, size_t ws_size,
                              hipStream_t stream)
{
  const float* x0        = (const float*)d_in[0];
  const float* x1        = (const float*)d_in[1];
  const float* w_norm0   = (const float*)d_in[2];
  const float* w_norm1   = (const float*)d_in[3];
  const float* in_proj_w = (const float*)d_in[4];
  const float* conv_w_f  = (const float*)d_in[5];
  const float* conv_b_f  = (const float*)d_in[6];
  const float* xproj_w_f = (const float*)d_in[7];
  const float* dtproj_w_f= (const float*)d_in[8];
  const float* dtproj_b_f= (const float*)d_in[9];
  const float* A_log_f   = (const float*)d_in[10];
  const float* D_f       = (const float*)d_in[11];
  const float* conv_w_bw = (const float*)d_in[12];
  const float* conv_b_bw = (const float*)d_in[13];
  const float* xproj_w_bw= (const float*)d_in[14];
  const float* dtproj_w_bw=(const float*)d_in[15];
  const float* dtproj_b_bw=(const float*)d_in[16];
  const float* A_log_bw  = (const float*)d_in[17];
  const float* D_bw      = (const float*)d_in[18];
  const float* norm_y_w  = (const float*)d_in[19];
  const float* out_proj_w= (const float*)d_in[20];
  const float* fc1_w     = (const float*)d_in[21];
  const float* dw_w      = (const float*)d_in[22];
  const float* dw_b      = (const float*)d_in[23];
  const float* fc2_w     = (const float*)d_in[24];
  float* out = (float*)d_out;
  float* ws  = (float*)d_ws;

  // workspace layout (floats), lifetime-based reuse
  float* h0   = ws + 0*BLD;   // -> later y_f
  float* h1   = ws + 1*BLD;   // -> later y_b
  float* xin  = ws + 2*BLD;   // -> later y_combined
  float* zbuf = ws + 3*BLD;
  float* xcf  = ws + 4*BLD;   // -> later m1 (BL*HID)
  float* xcb  = ws + 5*BLD;   // -> later m2 (BL*HID)
  float* dfb  = ws + 6*BLD;
  float* dbb  = ws + 7*BLD;
  float* xdf  = ws + 8*BLD;            // BL*32
  float* xdb  = ws + 8*BLD + (size_t)BL*32;
  float* yfv  = h0;
  float* ybv  = h1;
  float* ycomb= xin;
  float* m1   = xcf;
  float* m2   = xcb;

  // 1. RMSNorm x0 -> h0, x1 -> h1
  rms_kernel<<<dim3(BL,2), 64, 0, stream>>>(x0, w_norm0, h0, x1, w_norm1, h1);

  // 2. xz = h0 @ in_proj_w.T  (split: xin rows 0..255, z rows 256..511)
  gemm_abt<64,64,16,4,4,0><<<dim3(BL/64,4), 256, 0, stream>>>(
      h0, in_proj_w, xin, nullptr, nullptr, BL, 256, 256, 256, 0);
  gemm_abt<64,64,16,4,4,0><<<dim3(BL/64,4), 256, 0, stream>>>(
      h0, in_proj_w + (size_t)256*256, zbuf, nullptr, nullptr, BL, 256, 256, 256, 0);

  // 3. x_dbl = ctx @ xproj.T  (forward: h1; backward: flipped h1)
  gemm_abt<64,32,16,4,2,0><<<dim3(BL/64,1), 256, 0, stream>>>(
      h1, xproj_w_f, xdf, nullptr, nullptr, BL, 32, 256, 256, 0);
  gemm_abt<64,32,16,4,2,0><<<dim3(BL/64,1), 256, 0, stream>>>(
      h1, xproj_w_bw, xdb, nullptr, nullptr, BL, 32, 256, 256, 1);

  // 4. delta = softplus(dt @ dtproj.T + b)   (dt = x_dbl cols 0..15, lda=32)
  gemm_abt<64,64,16,4,4,2><<<dim3(BL/64,4), 256, 0, stream>>>(
      xdf, dtproj_w_f, dfb, nullptr, dtproj_b_f, BL, 256, 16, 32, 0);
  gemm_abt<64,64,16,4,4,2><<<dim3(BL/64,4), 256, 0, stream>>>(
      xdb, dtproj_w_bw, dbb, nullptr, dtproj_b_bw, BL, 256, 16, 32, 0);

  // 5. causal depthwise conv + silu (fwd from xin; bwd from flipped xin)
  conv_kernel<<<dim3(BLD/256,2), 256, 0, stream>>>(
      xin, conv_w_f, conv_b_f, xcf, conv_w_bw, conv_b_bw, xcb);

  // 6. selective scans (both directions concurrently)
  scan_kernel<<<dim3(32,2), 256, 0, stream>>>(
      xcf, dfb, xdf, A_log_f, D_f, yfv,
      xcb, dbb, xdb, A_log_bw, D_bw, ybv);

  // 7. combine + rmsnorm + gate
  combine_kernel<<<dim3(BL), 64, 0, stream>>>(yfv, ybv, zbuf, norm_y_w, ycomb);

  // 8. x = y @ out_proj.T + residual(x0)  -> d_out
  gemm_abt<64,64,16,4,4,1><<<dim3(BL/64,4), 256, 0, stream>>>(
      ycomb, out_proj_w, out, x0, nullptr, BL, 256, 256, 256, 0);

  // 9. m1 = x @ fc1.T
  gemm_abt<64,64,16,4,4,0><<<dim3(BL/64,2), 256, 0, stream>>>(
      out, fc1_w, m1, nullptr, nullptr, BL, 128, 256, 256, 0);

  // 10. m2 = silu(dwconv3(m1))
  dwconv3_kernel<<<dim3((BL*HID)/256), 256, 0, stream>>>(m1, dw_w, dw_b, m2);

  // 11. out = x + m2 @ fc2.T   (in-place add on d_out)
  gemm_abt<64,64,16,4,4,1><<<dim3(BL/64,4), 256, 0, stream>>>(
      m2, fc2_w, out, out, nullptr, BL, 256, 128, 128, 0);
}

// Round 2
// 491.445 us; speedup vs baseline: 2.3730x; 2.3730x over previous
//
#include <hip/hip_runtime.h>
#include <math.h>
#include <cstddef>

#define BB 4
#define LL 4096
#define DD 256
#define NST 8
#define RANK 16
#define HID 128
#define BL (BB*LL)          // 16384
#define BLD ((size_t)BL*DD) // 4194304
#define CH 64               // scan chunks
#define CLEN 64             // steps per chunk (CH*CLEN == LL)

__device__ __forceinline__ float siluf(float x){ return x / (1.f + __expf(-x)); }
__device__ __forceinline__ float softplusf_(float x){
  return fmaxf(x, 0.f) + log1pf(__expf(-fabsf(x)));
}

// ---------------- RMSNorm: one 64-thread wave per token, 4 floats/lane ----------
__global__ __launch_bounds__(64) void rms_kernel(
    const float* __restrict__ x0, const float* __restrict__ w0, float* __restrict__ o0,
    const float* __restrict__ x1, const float* __restrict__ w1, float* __restrict__ o1)
{
  const float* x; const float* w; float* o;
  if (blockIdx.y == 0){ x = x0; w = w0; o = o0; } else { x = x1; w = w1; o = o1; }
  size_t tok = blockIdx.x;
  int lane = threadIdx.x;
  float4 v = ((const float4*)(x + tok*DD))[lane];
  float s = v.x*v.x + v.y*v.y + v.z*v.z + v.w*v.w;
  #pragma unroll
  for (int m = 1; m < 64; m <<= 1) s += __shfl_xor(s, m, 64);
  float scale = 1.f / (sqrtf(s) * (1.f/16.f) + 1e-6f);
  float4 wv = ((const float4*)w)[lane];
  float4 r;
  r.x = v.x*scale*wv.x; r.y = v.y*scale*wv.y; r.z = v.z*scale*wv.z; r.w = v.w*scale*wv.w;
  ((float4*)(o + tok*DD))[lane] = r;
}

// ---------------- Generic tiled fp32 GEMM: C = A @ Bw^T  (+ epilogue) ------------
template<int BM, int BN, int BK, int TM, int TN, int EPI>
__global__ __launch_bounds__(256) void gemm_abt(
    const float* __restrict__ A, const float* __restrict__ Bw,
    float* __restrict__ C, const float* __restrict__ Add,
    const float* __restrict__ bias,
    int M, int N, int K, int lda, int flipA)
{
  __shared__ __align__(16) float As[BK][BM+4];
  __shared__ __align__(16) float Bs[BK][BN+4];
  int tid = threadIdx.x;
  int row0 = blockIdx.x * BM;
  int col0 = blockIdx.y * BN;
  int tr = tid / (BN/TN);
  int tc = tid % (BN/TN);
  float acc[TM][TN];
  #pragma unroll
  for (int i = 0; i < TM; i++)
    #pragma unroll
    for (int j = 0; j < TN; j++) acc[i][j] = 0.f;

  for (int k0 = 0; k0 < K; k0 += BK){
    #pragma unroll
    for (int e = tid; e < BM*BK; e += 256){
      int r = e / BK, c = e % BK;
      int pr = row0 + r;
      if (flipA){ int b = pr / LL; int t = pr % LL; pr = b*LL + (LL-1-t); }
      As[c][r] = A[(size_t)pr*lda + k0 + c];
    }
    #pragma unroll
    for (int e = tid; e < BN*BK; e += 256){
      int r = e / BK, c = e % BK;
      Bs[c][r] = Bw[(size_t)(col0 + r)*K + k0 + c];
    }
    __syncthreads();
    #pragma unroll
    for (int kk = 0; kk < BK; kk++){
      float a[TM], bf[TN];
      if constexpr (TM == 4){
        float4 av = *(const float4*)&As[kk][tr*TM];
        a[0]=av.x; a[1]=av.y; a[2]=av.z; a[3]=av.w;
      } else {
        #pragma unroll
        for (int i = 0; i < TM; i++) a[i] = As[kk][tr*TM + i];
      }
      if constexpr (TN == 4){
        float4 bv = *(const float4*)&Bs[kk][tc*TN];
        bf[0]=bv.x; bf[1]=bv.y; bf[2]=bv.z; bf[3]=bv.w;
      } else if constexpr (TN == 2){
        float2 bv = *(const float2*)&Bs[kk][tc*TN];
        bf[0]=bv.x; bf[1]=bv.y;
      } else {
        #pragma unroll
        for (int j = 0; j < TN; j++) bf[j] = Bs[kk][tc*TN + j];
      }
      #pragma unroll
      for (int i = 0; i < TM; i++)
        #pragma unroll
        for (int j = 0; j < TN; j++) acc[i][j] = fmaf(a[i], bf[j], acc[i][j]);
    }
    __syncthreads();
  }

  #pragma unroll
  for (int i = 0; i < TM; i++){
    int r = row0 + tr*TM + i;
    size_t base = (size_t)r*N + col0 + tc*TN;
    if constexpr (TN == 4){
      float4 v; v.x=acc[i][0]; v.y=acc[i][1]; v.z=acc[i][2]; v.w=acc[i][3];
      if constexpr (EPI == 1){
        float4 ad = *(const float4*)&Add[base];
        v.x += ad.x; v.y += ad.y; v.z += ad.z; v.w += ad.w;
      }
      if constexpr (EPI == 2){
        int cc = col0 + tc*TN;
        v.x = softplusf_(v.x + bias[cc+0]);
        v.y = softplusf_(v.y + bias[cc+1]);
        v.z = softplusf_(v.z + bias[cc+2]);
        v.w = softplusf_(v.w + bias[cc+3]);
      }
      *(float4*)&C[base] = v;
    } else {
      #pragma unroll
      for (int j = 0; j < TN; j++){
        float v = acc[i][j];
        if constexpr (EPI == 1) v += Add[base + j];
        if constexpr (EPI == 2) v = softplusf_(v + bias[col0 + tc*TN + j]);
        C[base + j] = v;
      }
    }
  }
}

// ---------------- Depthwise causal conv k=4 + SiLU (both directions) -------------
__global__ __launch_bounds__(256) void conv_kernel(
    const float* __restrict__ xin,
    const float* __restrict__ wf, const float* __restrict__ bf, float* __restrict__ of,
    const float* __restrict__ wb, const float* __restrict__ bb, float* __restrict__ ob)
{
  int dir = blockIdx.y;
  size_t gid = (size_t)blockIdx.x*256 + threadIdx.x;   // over BLD
  int c = (int)(gid % DD);
  int tok = (int)(gid / DD);
  int b = tok / LL, t = tok % LL;
  const float* w = dir ? wb : wf;
  const float* bi = dir ? bb : bf;
  float* o = dir ? ob : of;
  float acc = bi[c];
  #pragma unroll
  for (int k = 0; k < 4; k++){
    int tt = t - 3 + k;
    if (tt >= 0){
      int src_t = dir ? (LL-1-tt) : tt;
      acc = fmaf(w[c*4 + k], xin[((size_t)b*LL + src_t)*DD + c], acc);
    }
  }
  o[gid] = siluf(acc);
}

// =================== Chunk-parallel selective scan ===============================
// thread = one d (256/block); block = (chunk, b, dir). Each thread owns h[0..7].
// Layout of carry arrays: [dir][chunk][b][d][n] (n fastest), 2*64*4*2048 floats.

// Phase 1: local scan from h=0 -> Hout; P = exp(A * sum(delta))
__global__ __launch_bounds__(256) void scan_p1(
    const float* __restrict__ xcf, const float* __restrict__ dff,
    const float* __restrict__ xdf, const float* __restrict__ Alogf,
    const float* __restrict__ xcb, const float* __restrict__ dfb,
    const float* __restrict__ xdb, const float* __restrict__ Alogb,
    float* __restrict__ P, float* __restrict__ Hout)
{
  int chunk = blockIdx.x, b = blockIdx.y, dir = blockIdx.z;
  const float* xc   = dir ? xcb : xcf;
  const float* dl   = dir ? dfb : dff;
  const float* xd   = dir ? xdb : xdf;
  const float* Alog = dir ? Alogb : Alogf;
  int d = threadIdx.x;

  __shared__ float sXD[CLEN*32];
  {
    const float* xdp = xd + ((size_t)b*LL + (size_t)chunk*CLEN)*32;
    #pragma unroll
    for (int e = threadIdx.x; e < CLEN*32; e += 256) sXD[e] = xdp[e];
  }
  __syncthreads();

  float A[NST];
  #pragma unroll
  for (int n = 0; n < NST; n++) A[n] = -__expf(Alog[d*NST + n]);
  float h[NST];
  #pragma unroll
  for (int n = 0; n < NST; n++) h[n] = 0.f;
  float S = 0.f;

  const float* dp = dl + ((size_t)b*LL + (size_t)chunk*CLEN)*DD + d;
  const float* xp = xc + ((size_t)b*LL + (size_t)chunk*CLEN)*DD + d;

  const int U = 8;
  float pd[U], px[U];
  #pragma unroll
  for (int u = 0; u < U; u++){ pd[u] = dp[(size_t)u*DD]; px[u] = xp[(size_t)u*DD]; }

  for (int t0 = 0; t0 < CLEN; t0 += U){
    float nd[U], nx[U];
    if (t0 + U < CLEN){
      #pragma unroll
      for (int u = 0; u < U; u++){
        nd[u] = dp[(size_t)(t0+U+u)*DD]; nx[u] = xp[(size_t)(t0+U+u)*DD];
      }
    }
    #pragma unroll
    for (int u = 0; u < U; u++){
      float de = pd[u];
      S += de;
      float dux = de * px[u];
      int t = t0 + u;
      #pragma unroll
      for (int n = 0; n < NST; n++){
        float dA = __expf(de * A[n]);
        h[n] = fmaf(dA, h[n], dux * sXD[t*32 + 16 + n]);
      }
    }
    if (t0 + U < CLEN){
      #pragma unroll
      for (int u = 0; u < U; u++){ pd[u] = nd[u]; px[u] = nx[u]; }
    }
  }

  size_t ob = ((((size_t)dir*CH + chunk)*BB + b)*DD + d)*NST;
  float4 p0, p1h, h0v, h1v;
  p0.x = __expf(A[0]*S); p0.y = __expf(A[1]*S); p0.z = __expf(A[2]*S); p0.w = __expf(A[3]*S);
  p1h.x= __expf(A[4]*S); p1h.y= __expf(A[5]*S); p1h.z= __expf(A[6]*S); p1h.w= __expf(A[7]*S);
  h0v.x=h[0]; h0v.y=h[1]; h0v.z=h[2]; h0v.w=h[3];
  h1v.x=h[4]; h1v.y=h[5]; h1v.z=h[6]; h1v.w=h[7];
  *(float4*)&P[ob]      = p0;  *(float4*)&P[ob+4]    = p1h;
  *(float4*)&Hout[ob]   = h0v; *(float4*)&Hout[ob+4] = h1v;
}

// Phase 2: sequential carry over 64 chunks. thread = (dir,b,d,n), 16384 total.
__global__ __launch_bounds__(256) void scan_p2(
    const float* __restrict__ P, const float* __restrict__ Hout,
    float* __restrict__ Hin)
{
  int tid = blockIdx.x*256 + threadIdx.x;   // 0..16383
  int dir = tid >> 13;
  int b   = (tid >> 11) & 3;
  int dn  = tid & 2047;
  float h = 0.f;
  #pragma unroll 8
  for (int c = 0; c < CH; c++){
    size_t idx = (((size_t)dir*CH + c)*BB + b)*2048 + dn;
    Hin[idx] = h;
    h = fmaf(P[idx], h, Hout[idx]);
  }
}

// Phase 3: local scan seeded with Hin; writes y.
__global__ __launch_bounds__(256) void scan_p3(
    const float* __restrict__ xcf, const float* __restrict__ dff,
    const float* __restrict__ xdf, const float* __restrict__ Alogf,
    const float* __restrict__ Dfp, float* __restrict__ yf,
    const float* __restrict__ xcb, const float* __restrict__ dfb,
    const float* __restrict__ xdb, const float* __restrict__ Alogb,
    const float* __restrict__ Dbp, float* __restrict__ yb,
    const float* __restrict__ Hin)
{
  int chunk = blockIdx.x, b = blockIdx.y, dir = blockIdx.z;
  const float* xc   = dir ? xcb : xcf;
  const float* dl   = dir ? dfb : dff;
  const float* xd   = dir ? xdb : xdf;
  const float* Alog = dir ? Alogb : Alogf;
  const float* Dp   = dir ? Dbp : Dfp;
  float* y          = dir ? yb : yf;
  int d = threadIdx.x;

  __shared__ float sXD[CLEN*32];
  {
    const float* xdp = xd + ((size_t)b*LL + (size_t)chunk*CLEN)*32;
    #pragma unroll
    for (int e = threadIdx.x; e < CLEN*32; e += 256) sXD[e] = xdp[e];
  }
  __syncthreads();

  float A[NST];
  #pragma unroll
  for (int n = 0; n < NST; n++) A[n] = -__expf(Alog[d*NST + n]);
  float Dd = Dp[d];

  float h[NST];
  {
    size_t ib = ((((size_t)dir*CH + chunk)*BB + b)*DD + d)*NST;
    float4 a0 = *(const float4*)&Hin[ib];
    float4 a1 = *(const float4*)&Hin[ib+4];
    h[0]=a0.x; h[1]=a0.y; h[2]=a0.z; h[3]=a0.w;
    h[4]=a1.x; h[5]=a1.y; h[6]=a1.z; h[7]=a1.w;
  }

  const float* dp = dl + ((size_t)b*LL + (size_t)chunk*CLEN)*DD + d;
  const float* xp = xc + ((size_t)b*LL + (size_t)chunk*CLEN)*DD + d;
  float* yp       = y  + ((size_t)b*LL + (size_t)chunk*CLEN)*DD + d;

  const int U = 8;
  float pd[U], px[U];
  #pragma unroll
  for (int u = 0; u < U; u++){ pd[u] = dp[(size_t)u*DD]; px[u] = xp[(size_t)u*DD]; }

  for (int t0 = 0; t0 < CLEN; t0 += U){
    float nd[U], nx[U];
    if (t0 + U < CLEN){
      #pragma unroll
      for (int u = 0; u < U; u++){
        nd[u] = dp[(size_t)(t0+U+u)*DD]; nx[u] = xp[(size_t)(t0+U+u)*DD];
      }
    }
    #pragma unroll
    for (int u = 0; u < U; u++){
      float de = pd[u];
      float xv = px[u];
      float dux = de * xv;
      int t = t0 + u;
      float acc = xv * Dd;
      #pragma unroll
      for (int n = 0; n < NST; n++){
        float dA = __expf(de * A[n]);
        h[n] = fmaf(dA, h[n], dux * sXD[t*32 + 16 + n]);
        acc = fmaf(h[n], sXD[t*32 + 24 + n], acc);
      }
      yp[(size_t)t*DD] = acc;
    }
    if (t0 + U < CLEN){
      #pragma unroll
      for (int u = 0; u < U; u++){ pd[u] = nd[u]; px[u] = nx[u]; }
    }
  }
}

// ---------------- Combine: y=(yf+flip(yb))/2 -> rmsnorm -> *silu(z) --------------
__global__ __launch_bounds__(64) void combine_kernel(
    const float* __restrict__ yf, const float* __restrict__ yb,
    const float* __restrict__ z, const float* __restrict__ wn,
    float* __restrict__ out)
{
  size_t tok = blockIdx.x;
  int b = (int)(tok / LL), t = (int)(tok % LL);
  int lane = threadIdx.x;
  float4 a = ((const float4*)(yf + tok*DD))[lane];
  float4 c = ((const float4*)(yb + ((size_t)b*LL + (LL-1-t))*DD))[lane];
  float4 v;
  v.x=(a.x+c.x)*0.5f; v.y=(a.y+c.y)*0.5f; v.z=(a.z+c.z)*0.5f; v.w=(a.w+c.w)*0.5f;
  float s = v.x*v.x + v.y*v.y + v.z*v.z + v.w*v.w;
  #pragma unroll
  for (int m = 1; m < 64; m <<= 1) s += __shfl_xor(s, m, 64);
  float scale = 1.f / (sqrtf(s)*(1.f/16.f) + 1e-6f);
  float4 wv = ((const float4*)wn)[lane];
  float4 zv = ((const float4*)(z + tok*DD))[lane];
  float4 r;
  r.x = v.x*scale*wv.x*siluf(zv.x);
  r.y = v.y*scale*wv.y*siluf(zv.y);
  r.z = v.z*scale*wv.z*siluf(zv.z);
  r.w = v.w*scale*wv.w*siluf(zv.w);
  ((float4*)(out + tok*DD))[lane] = r;
}

// ---------------- FF depthwise conv k=3 pad(1,1) + SiLU --------------------------
__global__ __launch_bounds__(256) void dwconv3_kernel(
    const float* __restrict__ m, const float* __restrict__ w,
    const float* __restrict__ bi, float* __restrict__ o)
{
  size_t gid = (size_t)blockIdx.x*256 + threadIdx.x;  // over BL*HID
  int c = (int)(gid % HID);
  int tok = (int)(gid / HID);
  int b = tok / LL, t = tok % LL;
  float acc = bi[c];
  #pragma unroll
  for (int k = 0; k < 3; k++){
    int tt = t - 1 + k;
    if (tt >= 0 && tt < LL)
      acc = fmaf(w[c*3 + k], m[((size_t)b*LL + tt)*HID + c], acc);
  }
  o[gid] = siluf(acc);
}

extern "C" void kernel_launch(void* const* d_in, const int* in_sizes, int n_in,
                              void* d_out, int out_size, void* d_ws, size_t ws_size,
                              hipStream_t stream)
{
  const float* x0        = (const float*)d_in[0];
  const float* x1        = (const float*)d_in[1];
  const float* w_norm0   = (const float*)d_in[2];
  const float* w_norm1   = (const float*)d_in[3];
  const float* in_proj_w = (const float*)d_in[4];
  const float* conv_w_f  = (const float*)d_in[5];
  const float* conv_b_f  = (const float*)d_in[6];
  const float* xproj_w_f = (const float*)d_in[7];
  const float* dtproj_w_f= (const float*)d_in[8];
  const float* dtproj_b_f= (const float*)d_in[9];
  const float* A_log_f   = (const float*)d_in[10];
  const float* D_f       = (const float*)d_in[11];
  const float* conv_w_bw = (const float*)d_in[12];
  const float* conv_b_bw = (const float*)d_in[13];
  const float* xproj_w_bw= (const float*)d_in[14];
  const float* dtproj_w_bw=(const float*)d_in[15];
  const float* dtproj_b_bw=(const float*)d_in[16];
  const float* A_log_bw  = (const float*)d_in[17];
  const float* D_bw      = (const float*)d_in[18];
  const float* norm_y_w  = (const float*)d_in[19];
  const float* out_proj_w= (const float*)d_in[20];
  const float* fc1_w     = (const float*)d_in[21];
  const float* dw_w      = (const float*)d_in[22];
  const float* dw_b      = (const float*)d_in[23];
  const float* fc2_w     = (const float*)d_in[24];
  float* out = (float*)d_out;
  float* ws  = (float*)d_ws;

  // workspace layout (floats), lifetime-based reuse
  float* h0   = ws + 0*BLD;   // -> later y_f
  float* h1   = ws + 1*BLD;   // -> later y_b
  float* xin  = ws + 2*BLD;   // -> scan carries, then y_combined
  float* zbuf = ws + 3*BLD;
  float* xcf  = ws + 4*BLD;   // -> later m1 (BL*HID)
  float* xcb  = ws + 5*BLD;   // -> later m2 (BL*HID)
  float* dfb  = ws + 6*BLD;
  float* dbb  = ws + 7*BLD;
  float* xdf  = ws + 8*BLD;            // BL*32
  float* xdb  = ws + 8*BLD + (size_t)BL*32;
  float* yfv  = h0;
  float* ybv  = h1;
  float* ycomb= xin;
  float* m1   = xcf;
  float* m2   = xcb;
  // scan carry buffers live in the dead xin region (dead between conv and combine)
  const size_t CARRY = (size_t)2*CH*BB*DD*NST;   // 1,048,576 floats
  float* Pbuf = xin;
  float* Hout = xin + CARRY;
  float* Hin  = xin + 2*CARRY;                   // 12 MB total < 16.8 MB region

  // 1. RMSNorm x0 -> h0, x1 -> h1
  rms_kernel<<<dim3(BL,2), 64, 0, stream>>>(x0, w_norm0, h0, x1, w_norm1, h1);

  // 2. xz = h0 @ in_proj_w.T  (split: xin rows 0..255, z rows 256..511)
  gemm_abt<64,64,16,4,4,0><<<dim3(BL/64,4), 256, 0, stream>>>(
      h0, in_proj_w, xin, nullptr, nullptr, BL, 256, 256, 256, 0);
  gemm_abt<64,64,16,4,4,0><<<dim3(BL/64,4), 256, 0, stream>>>(
      h0, in_proj_w + (size_t)256*256, zbuf, nullptr, nullptr, BL, 256, 256, 256, 0);

  // 3. x_dbl = ctx @ xproj.T  (forward: h1; backward: flipped h1)
  gemm_abt<64,32,16,4,2,0><<<dim3(BL/64,1), 256, 0, stream>>>(
      h1, xproj_w_f, xdf, nullptr, nullptr, BL, 32, 256, 256, 0);
  gemm_abt<64,32,16,4,2,0><<<dim3(BL/64,1), 256, 0, stream>>>(
      h1, xproj_w_bw, xdb, nullptr, nullptr, BL, 32, 256, 256, 1);

  // 4. delta = softplus(dt @ dtproj.T + b)
  gemm_abt<64,64,16,4,4,2><<<dim3(BL/64,4), 256, 0, stream>>>(
      xdf, dtproj_w_f, dfb, nullptr, dtproj_b_f, BL, 256, 16, 32, 0);
  gemm_abt<64,64,16,4,4,2><<<dim3(BL/64,4), 256, 0, stream>>>(
      xdb, dtproj_w_bw, dbb, nullptr, dtproj_b_bw, BL, 256, 16, 32, 0);

  // 5. causal depthwise conv + silu (fwd from xin; bwd from flipped xin)
  conv_kernel<<<dim3(BLD/256,2), 256, 0, stream>>>(
      xin, conv_w_f, conv_b_f, xcf, conv_w_bw, conv_b_bw, xcb);

  // 6. chunk-parallel selective scan (both directions)
  scan_p1<<<dim3(CH,BB,2), 256, 0, stream>>>(
      xcf, dfb, xdf, A_log_f, xcb, dbb, xdb, A_log_bw, Pbuf, Hout);
  scan_p2<<<dim3(64), 256, 0, stream>>>(Pbuf, Hout, Hin);
  scan_p3<<<dim3(CH,BB,2), 256, 0, stream>>>(
      xcf, dfb, xdf, A_log_f, D_f, yfv,
      xcb, dbb, xdb, A_log_bw, D_bw, ybv, Hin);

  // 7. combine + rmsnorm + gate  (writes ycomb = xin region; carries now dead)
  combine_kernel<<<dim3(BL), 64, 0, stream>>>(yfv, ybv, zbuf, norm_y_w, ycomb);

  // 8. x = y @ out_proj.T + residual(x0)  -> d_out
  gemm_abt<64,64,16,4,4,1><<<dim3(BL/64,4), 256, 0, stream>>>(
      ycomb, out_proj_w, out, x0, nullptr, BL, 256, 256, 256, 0);

  // 9. m1 = x @ fc1.T
  gemm_abt<64,64,16,4,4,0><<<dim3(BL/64,2), 256, 0, stream>>>(
      out, fc1_w, m1, nullptr, nullptr, BL, 128, 256, 256, 0);

  // 10. m2 = silu(dwconv3(m1))
  dwconv3_kernel<<<dim3((BL*HID)/256), 256, 0, stream>>>(m1, dw_w, dw_b, m2);

  // 11. out = x + m2 @ fc2.T   (in-place add on d_out)
  gemm_abt<64,64,16,4,4,1><<<dim3(BL/64,4), 256, 0, stream>>>(
      m2, fc2_w, out, out, nullptr, BL, 256, 128, 128, 0);
}

// Round 3
// 373.342 us; speedup vs baseline: 3.1237x; 1.3163x over previous
//
#include <hip/hip_runtime.h>
#include <math.h>
#include <cstddef>

#define BB 4
#define LL 4096
#define DD 256
#define NST 8
#define RANK 16
#define HID 128
#define BL (BB*LL)          // 16384
#define BLD ((size_t)BL*DD) // 4194304
#define CH 64               // scan chunks
#define CLEN 64             // steps per chunk (CH*CLEN == LL)

typedef __bf16 bf16x8 __attribute__((ext_vector_type(8)));
typedef float  f32x4  __attribute__((ext_vector_type(4)));

__device__ __forceinline__ float siluf(float x){ return x / (1.f + __expf(-x)); }
__device__ __forceinline__ float softplusf_(float x){
  return fmaxf(x, 0.f) + log1pf(__expf(-fabsf(x)));
}
// fp32 -> bf16 bits, round-to-nearest-even
__device__ __forceinline__ unsigned short f2bf(float x){
  union { float f; unsigned u; } v; v.f = x;
  unsigned r = v.u + 0x7fffu + ((v.u >> 16) & 1u);
  return (unsigned short)(r >> 16);
}

// ---------------- RMSNorm: h0 -> bf16, h1 -> fp32 --------------------------------
__global__ __launch_bounds__(64) void rms_kernel(
    const float* __restrict__ x0, const float* __restrict__ w0, unsigned short* __restrict__ o0b,
    const float* __restrict__ x1, const float* __restrict__ w1, float* __restrict__ o1)
{
  const float* x; const float* w;
  if (blockIdx.y == 0){ x = x0; w = w0; } else { x = x1; w = w1; }
  size_t tok = blockIdx.x;
  int lane = threadIdx.x;
  float4 v = ((const float4*)(x + tok*DD))[lane];
  float s = v.x*v.x + v.y*v.y + v.z*v.z + v.w*v.w;
  #pragma unroll
  for (int m = 1; m < 64; m <<= 1) s += __shfl_xor(s, m, 64);
  float scale = 1.f / (sqrtf(s) * (1.f/16.f) + 1e-6f);
  float4 wv = ((const float4*)w)[lane];
  float4 r;
  r.x = v.x*scale*wv.x; r.y = v.y*scale*wv.y; r.z = v.z*scale*wv.z; r.w = v.w*scale*wv.w;
  if (blockIdx.y == 0){
    ushort4 o; o.x=f2bf(r.x); o.y=f2bf(r.y); o.z=f2bf(r.z); o.w=f2bf(r.w);
    ((ushort4*)(o0b + tok*DD))[lane] = o;
  } else {
    ((float4*)(o1 + tok*DD))[lane] = r;
  }
}

// ---------------- weight fp32->bf16 conversion -----------------------------------
__global__ __launch_bounds__(256) void cvt1_kernel(
    const float* __restrict__ s, unsigned short* __restrict__ d, int n)
{
  int i = blockIdx.x*256 + threadIdx.x;
  if (i < n) d[i] = f2bf(s[i]);
}
__global__ __launch_bounds__(256) void cvt3_kernel(
    const float* __restrict__ s0, const float* __restrict__ s1,
    const float* __restrict__ s2, unsigned short* __restrict__ d)
{
  int i = blockIdx.x*256 + threadIdx.x;   // 0..131071
  float v;
  if (i < 65536)       v = s0[i];
  else if (i < 98304)  v = s1[i - 65536];
  else                 v = s2[i - 98304];
  d[i] = f2bf(v);
}

// ---------------- bf16 MFMA GEMM: C = A @ Bw^T  (+ epilogue) ---------------------
// A: M x K bf16 row-major; Bw: N x K bf16 row-major; C: M x N fp32.
// EPI: 0 = C=acc ; 1 = C=acc+Add, also Cb=bf16(C) ; 2 = C=acc+Add
template<int EPI>
__global__ __launch_bounds__(256) void gemm_mfma(
    const unsigned short* __restrict__ A, const unsigned short* __restrict__ Bw,
    float* __restrict__ C, const float* __restrict__ Add,
    unsigned short* __restrict__ Cb, int M, int N, int K)
{
  constexpr int BM = 128, BN = 128, BK = 32, PAD = 8;
  __shared__ __align__(16) unsigned short As[BM][BK+PAD];
  __shared__ __align__(16) unsigned short Bs[BN][BK+PAD];
  int tid  = threadIdx.x;
  int row0 = blockIdx.x * BM;
  int col0 = blockIdx.y * BN;
  int wave = tid >> 6, lane = tid & 63;
  int wm = (wave >> 1) * 64, wn = (wave & 1) * 64;
  int lm = lane & 15, kq = lane >> 4;

  f32x4 acc[4][4];
  #pragma unroll
  for (int i = 0; i < 4; i++)
    #pragma unroll
    for (int j = 0; j < 4; j++) acc[i][j] = (f32x4){0.f,0.f,0.f,0.f};

  for (int k0 = 0; k0 < K; k0 += BK){
    #pragma unroll
    for (int e = tid; e < BM*4; e += 256){     // 4 x 8-elem chunks per row
      int r = e >> 2, c8 = (e & 3) * 8;
      *(int4*)&As[r][c8] = *(const int4*)&A[(size_t)(row0 + r)*K + k0 + c8];
    }
    #pragma unroll
    for (int e = tid; e < BN*4; e += 256){
      int r = e >> 2, c8 = (e & 3) * 8;
      *(int4*)&Bs[r][c8] = *(const int4*)&Bw[(size_t)(col0 + r)*K + k0 + c8];
    }
    __syncthreads();
    bf16x8 af[4], bf[4];
    #pragma unroll
    for (int i = 0; i < 4; i++) af[i] = *(const bf16x8*)&As[wm + i*16 + lm][kq*8];
    #pragma unroll
    for (int j = 0; j < 4; j++) bf[j] = *(const bf16x8*)&Bs[wn + j*16 + lm][kq*8];
    #pragma unroll
    for (int i = 0; i < 4; i++)
      #pragma unroll
      for (int j = 0; j < 4; j++)
        acc[i][j] = __builtin_amdgcn_mfma_f32_16x16x32_bf16(af[i], bf[j], acc[i][j], 0, 0, 0);
    __syncthreads();
  }

  // C/D layout: col = lane&15, row = (lane>>4)*4 + reg   [m89-verified]
  #pragma unroll
  for (int i = 0; i < 4; i++){
    int rbase = row0 + wm + i*16 + kq*4;
    #pragma unroll
    for (int j = 0; j < 4; j++){
      int col = col0 + wn + j*16 + lm;
      #pragma unroll
      for (int r = 0; r < 4; r++){
        size_t idx = (size_t)(rbase + r)*N + col;
        float v = acc[i][j][r];
        if constexpr (EPI >= 1) v += Add[idx];
        C[idx] = v;
        if constexpr (EPI == 1) Cb[idx] = f2bf(v);
      }
    }
  }
}

// ---------------- fp32 GEMM (small: xproj / dtproj) ------------------------------
template<int BM, int BN, int BK, int TM, int TN, int EPI>
__global__ __launch_bounds__(256) void gemm_abt(
    const float* __restrict__ A, const float* __restrict__ Bw,
    float* __restrict__ C, const float* __restrict__ Add,
    const float* __restrict__ bias,
    int M, int N, int K, int lda, int flipA)
{
  __shared__ __align__(16) float As[BK][BM+4];
  __shared__ __align__(16) float Bs[BK][BN+4];
  int tid = threadIdx.x;
  int row0 = blockIdx.x * BM;
  int col0 = blockIdx.y * BN;
  int tr = tid / (BN/TN);
  int tc = tid % (BN/TN);
  float acc[TM][TN];
  #pragma unroll
  for (int i = 0; i < TM; i++)
    #pragma unroll
    for (int j = 0; j < TN; j++) acc[i][j] = 0.f;

  for (int k0 = 0; k0 < K; k0 += BK){
    #pragma unroll
    for (int e = tid; e < BM*BK; e += 256){
      int r = e / BK, c = e % BK;
      int pr = row0 + r;
      if (flipA){ int b = pr / LL; int t = pr % LL; pr = b*LL + (LL-1-t); }
      As[c][r] = A[(size_t)pr*lda + k0 + c];
    }
    #pragma unroll
    for (int e = tid; e < BN*BK; e += 256){
      int r = e / BK, c = e % BK;
      Bs[c][r] = Bw[(size_t)(col0 + r)*K + k0 + c];
    }
    __syncthreads();
    #pragma unroll
    for (int kk = 0; kk < BK; kk++){
      float a[TM], bf[TN];
      #pragma unroll
      for (int i = 0; i < TM; i++) a[i] = As[kk][tr*TM + i];
      #pragma unroll
      for (int j = 0; j < TN; j++) bf[j] = Bs[kk][tc*TN + j];
      #pragma unroll
      for (int i = 0; i < TM; i++)
        #pragma unroll
        for (int j = 0; j < TN; j++) acc[i][j] = fmaf(a[i], bf[j], acc[i][j]);
    }
    __syncthreads();
  }

  #pragma unroll
  for (int i = 0; i < TM; i++){
    int r = row0 + tr*TM + i;
    size_t base = (size_t)r*N + col0 + tc*TN;
    #pragma unroll
    for (int j = 0; j < TN; j++){
      float v = acc[i][j];
      if constexpr (EPI == 1) v += Add[base + j];
      if constexpr (EPI == 2) v = softplusf_(v + bias[col0 + tc*TN + j]);
      C[base + j] = v;
    }
  }
}

// ---------------- Depthwise causal conv k=4 + SiLU (both directions) -------------
__global__ __launch_bounds__(256) void conv_kernel(
    const float* __restrict__ xin,
    const float* __restrict__ wf, const float* __restrict__ bf, float* __restrict__ of,
    const float* __restrict__ wb, const float* __restrict__ bb, float* __restrict__ ob)
{
  int dir = blockIdx.y;
  size_t gid = (size_t)blockIdx.x*256 + threadIdx.x;   // over BLD
  int c = (int)(gid % DD);
  int tok = (int)(gid / DD);
  int b = tok / LL, t = tok % LL;
  const float* w = dir ? wb : wf;
  const float* bi = dir ? bb : bf;
  float* o = dir ? ob : of;
  float acc = bi[c];
  #pragma unroll
  for (int k = 0; k < 4; k++){
    int tt = t - 3 + k;
    if (tt >= 0){
      int src_t = dir ? (LL-1-tt) : tt;
      acc = fmaf(w[c*4 + k], xin[((size_t)b*LL + src_t)*DD + c], acc);
    }
  }
  o[gid] = siluf(acc);
}

// =================== Chunk-parallel selective scan ===============================
__global__ __launch_bounds__(256) void scan_p1(
    const float* __restrict__ xcf, const float* __restrict__ dff,
    const float* __restrict__ xdf, const float* __restrict__ Alogf,
    const float* __restrict__ xcb, const float* __restrict__ dfb,
    const float* __restrict__ xdb, const float* __restrict__ Alogb,
    float* __restrict__ P, float* __restrict__ Hout)
{
  int chunk = blockIdx.x, b = blockIdx.y, dir = blockIdx.z;
  const float* xc   = dir ? xcb : xcf;
  const float* dl   = dir ? dfb : dff;
  const float* xd   = dir ? xdb : xdf;
  const float* Alog = dir ? Alogb : Alogf;
  int d = threadIdx.x;

  __shared__ float sXD[CLEN*32];
  {
    const float* xdp = xd + ((size_t)b*LL + (size_t)chunk*CLEN)*32;
    #pragma unroll
    for (int e = threadIdx.x; e < CLEN*32; e += 256) sXD[e] = xdp[e];
  }
  __syncthreads();

  float A[NST];
  #pragma unroll
  for (int n = 0; n < NST; n++) A[n] = -__expf(Alog[d*NST + n]);
  float h[NST];
  #pragma unroll
  for (int n = 0; n < NST; n++) h[n] = 0.f;
  float S = 0.f;

  const float* dp = dl + ((size_t)b*LL + (size_t)chunk*CLEN)*DD + d;
  const float* xp = xc + ((size_t)b*LL + (size_t)chunk*CLEN)*DD + d;

  const int U = 8;
  float pd[U], px[U];
  #pragma unroll
  for (int u = 0; u < U; u++){ pd[u] = dp[(size_t)u*DD]; px[u] = xp[(size_t)u*DD]; }

  for (int t0 = 0; t0 < CLEN; t0 += U){
    float nd[U], nx[U];
    if (t0 + U < CLEN){
      #pragma unroll
      for (int u = 0; u < U; u++){
        nd[u] = dp[(size_t)(t0+U+u)*DD]; nx[u] = xp[(size_t)(t0+U+u)*DD];
      }
    }
    #pragma unroll
    for (int u = 0; u < U; u++){
      float de = pd[u];
      S += de;
      float dux = de * px[u];
      int t = t0 + u;
      #pragma unroll
      for (int n = 0; n < NST; n++){
        float dA = __expf(de * A[n]);
        h[n] = fmaf(dA, h[n], dux * sXD[t*32 + 16 + n]);
      }
    }
    if (t0 + U < CLEN){
      #pragma unroll
      for (int u = 0; u < U; u++){ pd[u] = nd[u]; px[u] = nx[u]; }
    }
  }

  size_t ob = ((((size_t)dir*CH + chunk)*BB + b)*DD + d)*NST;
  float4 p0, p1h, h0v, h1v;
  p0.x = __expf(A[0]*S); p0.y = __expf(A[1]*S); p0.z = __expf(A[2]*S); p0.w = __expf(A[3]*S);
  p1h.x= __expf(A[4]*S); p1h.y= __expf(A[5]*S); p1h.z= __expf(A[6]*S); p1h.w= __expf(A[7]*S);
  h0v.x=h[0]; h0v.y=h[1]; h0v.z=h[2]; h0v.w=h[3];
  h1v.x=h[4]; h1v.y=h[5]; h1v.z=h[6]; h1v.w=h[7];
  *(float4*)&P[ob]      = p0;  *(float4*)&P[ob+4]    = p1h;
  *(float4*)&Hout[ob]   = h0v; *(float4*)&Hout[ob+4] = h1v;
}

__global__ __launch_bounds__(256) void scan_p2(
    const float* __restrict__ P, const float* __restrict__ Hout,
    float* __restrict__ Hin)
{
  int tid = blockIdx.x*256 + threadIdx.x;   // 0..16383
  int dir = tid >> 13;
  int b   = (tid >> 11) & 3;
  int dn  = tid & 2047;
  float h = 0.f;
  #pragma unroll 8
  for (int c = 0; c < CH; c++){
    size_t idx = (((size_t)dir*CH + c)*BB + b)*2048 + dn;
    Hin[idx] = h;
    h = fmaf(P[idx], h, Hout[idx]);
  }
}

__global__ __launch_bounds__(256) void scan_p3(
    const float* __restrict__ xcf, const float* __restrict__ dff,
    const float* __restrict__ xdf, const float* __restrict__ Alogf,
    const float* __restrict__ Dfp, float* __restrict__ yf,
    const float* __restrict__ xcb, const float* __restrict__ dfb,
    const float* __restrict__ xdb, const float* __restrict__ Alogb,
    const float* __restrict__ Dbp, float* __restrict__ yb,
    const float* __restrict__ Hin)
{
  int chunk = blockIdx.x, b = blockIdx.y, dir = blockIdx.z;
  const float* xc   = dir ? xcb : xcf;
  const float* dl   = dir ? dfb : dff;
  const float* xd   = dir ? xdb : xdf;
  const float* Alog = dir ? Alogb : Alogf;
  const float* Dp   = dir ? Dbp : Dfp;
  float* y          = dir ? yb : yf;
  int d = threadIdx.x;

  __shared__ float sXD[CLEN*32];
  {
    const float* xdp = xd + ((size_t)b*LL + (size_t)chunk*CLEN)*32;
    #pragma unroll
    for (int e = threadIdx.x; e < CLEN*32; e += 256) sXD[e] = xdp[e];
  }
  __syncthreads();

  float A[NST];
  #pragma unroll
  for (int n = 0; n < NST; n++) A[n] = -__expf(Alog[d*NST + n]);
  float Dd = Dp[d];

  float h[NST];
  {
    size_t ib = ((((size_t)dir*CH + chunk)*BB + b)*DD + d)*NST;
    float4 a0 = *(const float4*)&Hin[ib];
    float4 a1 = *(const float4*)&Hin[ib+4];
    h[0]=a0.x; h[1]=a0.y; h[2]=a0.z; h[3]=a0.w;
    h[4]=a1.x; h[5]=a1.y; h[6]=a1.z; h[7]=a1.w;
  }

  const float* dp = dl + ((size_t)b*LL + (size_t)chunk*CLEN)*DD + d;
  const float* xp = xc + ((size_t)b*LL + (size_t)chunk*CLEN)*DD + d;
  float* yp       = y  + ((size_t)b*LL + (size_t)chunk*CLEN)*DD + d;

  const int U = 8;
  float pd[U], px[U];
  #pragma unroll
  for (int u = 0; u < U; u++){ pd[u] = dp[(size_t)u*DD]; px[u] = xp[(size_t)u*DD]; }

  for (int t0 = 0; t0 < CLEN; t0 += U){
    float nd[U], nx[U];
    if (t0 + U < CLEN){
      #pragma unroll
      for (int u = 0; u < U; u++){
        nd[u] = dp[(size_t)(t0+U+u)*DD]; nx[u] = xp[(size_t)(t0+U+u)*DD];
      }
    }
    #pragma unroll
    for (int u = 0; u < U; u++){
      float de = pd[u];
      float xv = px[u];
      float dux = de * xv;
      int t = t0 + u;
      float acc = xv * Dd;
      #pragma unroll
      for (int n = 0; n < NST; n++){
        float dA = __expf(de * A[n]);
        h[n] = fmaf(dA, h[n], dux * sXD[t*32 + 16 + n]);
        acc = fmaf(h[n], sXD[t*32 + 24 + n], acc);
      }
      yp[(size_t)t*DD] = acc;
    }
    if (t0 + U < CLEN){
      #pragma unroll
      for (int u = 0; u < U; u++){ pd[u] = nd[u]; px[u] = nx[u]; }
    }
  }
}

// ---------------- Combine: y=(yf+flip(yb))/2 -> rmsnorm -> *silu(z) -> bf16 ------
__global__ __launch_bounds__(64) void combine_kernel(
    const float* __restrict__ yf, const float* __restrict__ yb,
    const float* __restrict__ z, const float* __restrict__ wn,
    unsigned short* __restrict__ outb)
{
  size_t tok = blockIdx.x;
  int b = (int)(tok / LL), t = (int)(tok % LL);
  int lane = threadIdx.x;
  float4 a = ((const float4*)(yf + tok*DD))[lane];
  float4 c = ((const float4*)(yb + ((size_t)b*LL + (LL-1-t))*DD))[lane];
  float4 v;
  v.x=(a.x+c.x)*0.5f; v.y=(a.y+c.y)*0.5f; v.z=(a.z+c.z)*0.5f; v.w=(a.w+c.w)*0.5f;
  float s = v.x*v.x + v.y*v.y + v.z*v.z + v.w*v.w;
  #pragma unroll
  for (int m = 1; m < 64; m <<= 1) s += __shfl_xor(s, m, 64);
  float scale = 1.f / (sqrtf(s)*(1.f/16.f) + 1e-6f);
  float4 wv = ((const float4*)wn)[lane];
  float4 zv = ((const float4*)(z + tok*DD))[lane];
  ushort4 r;
  r.x = f2bf(v.x*scale*wv.x*siluf(zv.x));
  r.y = f2bf(v.y*scale*wv.y*siluf(zv.y));
  r.z = f2bf(v.z*scale*wv.z*siluf(zv.z));
  r.w = f2bf(v.w*scale*wv.w*siluf(zv.w));
  ((ushort4*)(outb + tok*DD))[lane] = r;
}

// ---------------- FF depthwise conv k=3 pad(1,1) + SiLU -> bf16 ------------------
__global__ __launch_bounds__(256) void dwconv3_kernel(
    const float* __restrict__ m, const float* __restrict__ w,
    const float* __restrict__ bi, unsigned short* __restrict__ o)
{
  size_t gid = (size_t)blockIdx.x*256 + threadIdx.x;  // over BL*HID
  int c = (int)(gid % HID);
  int tok = (int)(gid / HID);
  int b = tok / LL, t = tok % LL;
  float acc = bi[c];
  #pragma unroll
  for (int k = 0; k < 3; k++){
    int tt = t - 1 + k;
    if (tt >= 0 && tt < LL)
      acc = fmaf(w[c*3 + k], m[((size_t)b*LL + tt)*HID + c], acc);
  }
  o[gid] = f2bf(siluf(acc));
}

extern "C" void kernel_launch(void* const* d_in, const int* in_sizes, int n_in,
                              void* d_out, int out_size, void* d_ws, size_t ws_size,
                              hipStream_t stream)
{
  const float* x0        = (const float*)d_in[0];
  const float* x1        = (const float*)d_in[1];
  const float* w_norm0   = (const float*)d_in[2];
  const float* w_norm1   = (const float*)d_in[3];
  const float* in_proj_w = (const float*)d_in[4];
  const float* conv_w_f  = (const float*)d_in[5];
  const float* conv_b_f  = (const float*)d_in[6];
  const float* xproj_w_f = (const float*)d_in[7];
  const float* dtproj_w_f= (const float*)d_in[8];
  const float* dtproj_b_f= (const float*)d_in[9];
  const float* A_log_f   = (const float*)d_in[10];
  const float* D_f       = (const float*)d_in[11];
  const float* conv_w_bw = (const float*)d_in[12];
  const float* conv_b_bw = (const float*)d_in[13];
  const float* xproj_w_bw= (const float*)d_in[14];
  const float* dtproj_w_bw=(const float*)d_in[15];
  const float* dtproj_b_bw=(const float*)d_in[16];
  const float* A_log_bw  = (const float*)d_in[17];
  const float* D_bw      = (const float*)d_in[18];
  const float* norm_y_w  = (const float*)d_in[19];
  const float* out_proj_w= (const float*)d_in[20];
  const float* fc1_w     = (const float*)d_in[21];
  const float* dw_w      = (const float*)d_in[22];
  const float* dw_b      = (const float*)d_in[23];
  const float* fc2_w     = (const float*)d_in[24];
  float* out = (float*)d_out;
  float* ws  = (float*)d_ws;

  // region map (floats), lifetime-reused; footprint identical to R1
  float* r0 = ws + 0*BLD;   // h0b (bf16) -> yfv
  float* r1 = ws + 1*BLD;   // h1 -> ybv
  float* r2 = ws + 2*BLD;   // xin -> scan carries -> ycomb_b (bf16)
  float* r3 = ws + 3*BLD;   // zbuf -> xb (bf16) + wbuf2 (bf16)
  float* r4 = ws + 4*BLD;   // xcf -> m1
  float* r5 = ws + 5*BLD;   // xcb -> m2b (bf16)
  float* r6 = ws + 6*BLD;   // wbuf1 (bf16) -> dfb
  float* r7 = ws + 7*BLD;   // dbb
  float* xdf  = ws + 8*BLD;            // BL*32
  float* xdb  = ws + 8*BLD + (size_t)BL*32;

  unsigned short* h0b   = (unsigned short*)r0;
  float*          h1    = r1;
  float*          xin   = r2;
  float*          zbuf  = r3;
  float*          xcf   = r4;
  float*          xcb   = r5;
  unsigned short* wbuf1 = (unsigned short*)r6;   // in_proj_w bf16 (131072)
  float*          dfb   = r6;
  float*          dbb   = r7;
  float*          yfv   = r0;
  float*          ybv   = r1;
  const size_t CARRY = (size_t)2*CH*BB*DD*NST;   // 1,048,576 floats
  float* Pbuf = r2;
  float* Hout = r2 + CARRY;
  float* Hin  = r2 + 2*CARRY;
  unsigned short* ycomb_b = (unsigned short*)r2;
  unsigned short* xb      = (unsigned short*)r3;            // BLD bf16 = 2M floats
  unsigned short* wbuf2   = (unsigned short*)(r3 + 2*1048576 + 65536); // after xb
  unsigned short* wb_out  = wbuf2;            // 65536
  unsigned short* wb_fc1  = wbuf2 + 65536;    // 32768
  unsigned short* wb_fc2  = wbuf2 + 98304;    // 32768
  float*          m1      = r4;
  unsigned short* m2b     = (unsigned short*)r5;

  // 1. RMSNorm x0 -> h0b (bf16), x1 -> h1 (fp32)
  rms_kernel<<<dim3(BL,2), 64, 0, stream>>>(x0, w_norm0, h0b, x1, w_norm1, h1);

  // 2. convert in_proj_w to bf16; xz = h0 @ in_proj_w.T  (two halves)
  cvt1_kernel<<<dim3(512), 256, 0, stream>>>(in_proj_w, wbuf1, 131072);
  gemm_mfma<0><<<dim3(BL/128, 2), 256, 0, stream>>>(
      h0b, wbuf1, xin, nullptr, nullptr, BL, 256, 256);
  gemm_mfma<0><<<dim3(BL/128, 2), 256, 0, stream>>>(
      h0b, wbuf1 + 65536, zbuf, nullptr, nullptr, BL, 256, 256);

  // 3. x_dbl = ctx @ xproj.T (fp32; forward h1, backward flipped h1)
  gemm_abt<64,32,16,4,2,0><<<dim3(BL/64,1), 256, 0, stream>>>(
      h1, xproj_w_f, xdf, nullptr, nullptr, BL, 32, 256, 256, 0);
  gemm_abt<64,32,16,4,2,0><<<dim3(BL/64,1), 256, 0, stream>>>(
      h1, xproj_w_bw, xdb, nullptr, nullptr, BL, 32, 256, 256, 1);

  // 4. delta = softplus(dt @ dtproj.T + b)   (overwrites wbuf1 region — in_proj done)
  gemm_abt<64,64,16,4,4,2><<<dim3(BL/64,4), 256, 0, stream>>>(
      xdf, dtproj_w_f, dfb, nullptr, dtproj_b_f, BL, 256, 16, 32, 0);
  gemm_abt<64,64,16,4,4,2><<<dim3(BL/64,4), 256, 0, stream>>>(
      xdb, dtproj_w_bw, dbb, nullptr, dtproj_b_bw, BL, 256, 16, 32, 0);

  // 5. causal depthwise conv + silu
  conv_kernel<<<dim3(BLD/256,2), 256, 0, stream>>>(
      xin, conv_w_f, conv_b_f, xcf, conv_w_bw, conv_b_bw, xcb);

  // 6. chunk-parallel selective scan
  scan_p1<<<dim3(CH,BB,2), 256, 0, stream>>>(
      xcf, dfb, xdf, A_log_f, xcb, dbb, xdb, A_log_bw, Pbuf, Hout);
  scan_p2<<<dim3(64), 256, 0, stream>>>(Pbuf, Hout, Hin);
  scan_p3<<<dim3(CH,BB,2), 256, 0, stream>>>(
      xcf, dfb, xdf, A_log_f, D_f, yfv,
      xcb, dbb, xdb, A_log_bw, D_bw, ybv, Hin);

  // 7. combine + rmsnorm + gate -> bf16 (r2; carries dead)
  combine_kernel<<<dim3(BL), 64, 0, stream>>>(yfv, ybv, zbuf, norm_y_w, ycomb_b);

  // 8. convert remaining weights (r3 zbuf dead); out_proj + residual
  cvt3_kernel<<<dim3(512), 256, 0, stream>>>(out_proj_w, fc1_w, fc2_w, wbuf2);
  gemm_mfma<1><<<dim3(BL/128, 2), 256, 0, stream>>>(
      ycomb_b, wb_out, out, x0, xb, BL, 256, 256);

  // 9. m1 = x @ fc1.T (fp32 out)
  gemm_mfma<0><<<dim3(BL/128, 1), 256, 0, stream>>>(
      xb, wb_fc1, m1, nullptr, nullptr, BL, 128, 256);

  // 10. m2 = silu(dwconv3(m1)) -> bf16
  dwconv3_kernel<<<dim3((BL*HID)/256), 256, 0, stream>>>(m1, dw_w, dw_b, m2b);

  // 11. out = x + m2 @ fc2.T
  gemm_mfma<2><<<dim3(BL/128, 2), 256, 0, stream>>>(
      m2b, wb_fc2, out, out, nullptr, BL, 256, 128);
}